// Round 13
// baseline (271.456 us; speedup 1.0000x reference)
//
#include <hip/hip_runtime.h>

#define TEN 10

typedef float v2f __attribute__((ext_vector_type(2)));

// ---- VOP3P op_sel helpers: fold broadcasts into the packed op -------------
// src0-broadcast (x-halves feeding WBUILD):
#define PK_MUL_S0LO(d,s0,s1)   asm("v_pk_mul_f32 %0, %1, %2 op_sel:[0,0] op_sel_hi:[0,1]"         : "=v"(d)  : "v"(s0), "v"(s1))
#define PK_FMA_S0LO(acc,s0,s1) asm("v_pk_fma_f32 %0, %1, %2, %0 op_sel:[0,0,0] op_sel_hi:[0,1,1]" : "+v"(acc) : "v"(s0), "v"(s1))
#define PK_FMA_S0HI(acc,s0,s1) asm("v_pk_fma_f32 %0, %1, %2, %0 op_sel:[1,0,0] op_sel_hi:[1,1,1]" : "+v"(acc) : "v"(s0), "v"(s1))
// src1-broadcast (w.lo / w.hi feeding STREAM):
#define PK_MUL_S1LO(d,s0,s1)   asm("v_pk_mul_f32 %0, %1, %2 op_sel:[0,0] op_sel_hi:[1,0]"         : "=v"(d)  : "v"(s0), "v"(s1))
#define PK_MUL_S1HI(d,s0,s1)   asm("v_pk_mul_f32 %0, %1, %2 op_sel:[0,1] op_sel_hi:[1,1]"         : "=v"(d)  : "v"(s0), "v"(s1))
#define PK_FMA_S1LO(acc,s0,s1) asm("v_pk_fma_f32 %0, %1, %2, %0 op_sel:[0,0,0] op_sel_hi:[1,0,1]" : "+v"(acc) : "v"(s0), "v"(s1))
#define PK_FMA_S1HI(acc,s0,s1) asm("v_pk_fma_f32 %0, %1, %2, %0 op_sel:[0,1,0] op_sel_hi:[1,1,1]" : "+v"(acc) : "v"(s0), "v"(s1))

// ---------------------------------------------------------------------------
// Phase A = r8's main loop VERBATIM (best measured: 173.6us, 51 cyc/step),
// repackaged as 512-thread blocks, grid 256, 96 chunks/block:
//   - per-wave code, occupancy (8 waves/CU = 2/SIMD), and 256-reg budget
//     IDENTICAL to r8's 2x256-thread blocks (r11's fused run confirmed:
//     VALU-busy time 64.5us == r8's 64.2us at this config);
//   - in-block tree folds 96 -> 1, so only 256 block matrices ship to the
//     final kernel -> r6's cheapest-measured final (chain-4 + tree64)
//     instead of r12's 512-matrix read (+6us) or r8's chain-8 (+10us).
// r11/r12 gap decomposition: fixed harness ~77.5us, launch ~10us, final
// dispatch = the only movable part. This is the last unmeasured combo.
// LDS: M col-major, col stride 12 (16B-aligned cols -> b128/b64), slot
// stride 132 (2-way bank alias, measured free per r9). Same-address 5-lane
// group reads broadcast. No __syncthreads in the main loop.
// ---------------------------------------------------------------------------
__global__ __attribute__((amdgpu_flat_work_group_size(512, 512),
                          amdgpu_waves_per_eu(2, 2)))
void automaton_chunks(const float* __restrict__ x, const float* __restrict__ P,
                      float* __restrict__ outBlk, long long T, int C)
{
    // main loop: 96 slots * 132 = 12672. tree: T0 = 96*120 = 11520 @0,
    // ping-pong dst @11520 (48*120 = 5760) -> extent 17280 floats (69.1KB).
    __shared__ __align__(16) float lds[17280];

    const int tid  = threadIdx.x;     // 0..511
    const int wave = tid >> 6;        // 0..7
    const int lane = tid & 63;
    const int grp  = lane / 5;        // 0..11 active, 12 => idle lanes 60..63
    const int sub  = lane % 5;
    const bool active = (grp < 12);
    const int cib  = wave * 12 + grp; // chunk within block 0..95
    const int j0 = 2 * sub, j1 = j0 + 1;

    v2f p2[TEN][TEN];                 // p2[k][a] = {P[k][a][j0], P[k][a][j1]}
    v2f m2[2][5];                     // m2[c][i] = {M[2i][jc], M[2i+1][jc]}
    int Lc = 0;
    const v2f* xp = nullptr;
    float* slot = lds + (active ? cib : 0) * 132;   // read base (col a at +12a)
    float* wb0  = slot + j0 * 12;                   // write base (own col j0; j1 at +12)

    if (active) {
        const long long chunk = (long long)blockIdx.x * 96 + cib;
        const long long s0 = chunk * T / C;
        const long long s1 = (chunk + 1) * T / C;
        Lc = (int)(s1 - s0);
        xp = reinterpret_cast<const v2f*>(x) + s0 * 5;
#pragma unroll
        for (int k = 0; k < TEN; ++k)
#pragma unroll
            for (int a = 0; a < TEN; ++a) {
                const float2 v = *reinterpret_cast<const float2*>(P + k * 100 + a * TEN + j0);
                p2[k][a].x = v.x;
                p2[k][a].y = v.y;
            }
#pragma unroll
        for (int c = 0; c < 2; ++c)
#pragma unroll
            for (int i = 0; i < 5; ++i) {
                const int jc = 2 * sub + c;
                m2[c][i].x = (2 * i     == jc) ? 1.0f : 0.0f;
                m2[c][i].y = (2 * i + 1 == jc) ? 1.0f : 0.0f;
            }
    }

    v2f nxv0, nxv1, nxv2, nxv3, nxv4;
    if (active) {
        nxv0 = xp[0]; nxv1 = xp[1]; nxv2 = xp[2]; nxv3 = xp[3]; nxv4 = xp[4];
        xp += 5;
    }

    if (active) {
#pragma unroll 1
        for (int s = 0; s < Lc; ++s) {
            // 1) publish own columns of M_t: 10x ds_write_b64 straight from m2
            {
                *reinterpret_cast<v2f*>(wb0 + 0)  = m2[0][0];
                *reinterpret_cast<v2f*>(wb0 + 2)  = m2[0][1];
                *reinterpret_cast<v2f*>(wb0 + 4)  = m2[0][2];
                *reinterpret_cast<v2f*>(wb0 + 6)  = m2[0][3];
                *reinterpret_cast<v2f*>(wb0 + 8)  = m2[0][4];
                *reinterpret_cast<v2f*>(wb0 + 12) = m2[1][0];
                *reinterpret_cast<v2f*>(wb0 + 14) = m2[1][1];
                *reinterpret_cast<v2f*>(wb0 + 16) = m2[1][2];
                *reinterpret_cast<v2f*>(wb0 + 18) = m2[1][3];
                *reinterpret_cast<v2f*>(wb0 + 20) = m2[1][4];
            }
            __builtin_amdgcn_wave_barrier();   // write -> read order (in-order DS pipe)

            // 2) prefetch next x into px (full-iteration gap covers HBM latency)
            v2f px0, px1, px2, px3, px4;
            if (s + 1 < Lc) {
                px0 = xp[0]; px1 = xp[1]; px2 = xp[2]; px3 = xp[3]; px4 = xp[4];
                xp += 5;
            }

            // 3) fused per-a: read column a of M_t, build w via op_sel
            //    x-broadcasts, stream into m2 via op_sel w-broadcasts.
#pragma unroll
            for (int a = 0; a < TEN; ++a) {
                union { float4 q; v2f h[2]; } u0, u1;
                union { float2 f; v2f v;   } u2;
                u0.q = *reinterpret_cast<const float4*>(slot + a * 12);
                u1.q = *reinterpret_cast<const float4*>(slot + a * 12 + 4);
                u2.f = *reinterpret_cast<const float2*>(slot + a * 12 + 8);
                const v2f c0 = u0.h[0], c1 = u0.h[1], c2 = u1.h[0], c3 = u1.h[1], c4 = u2.v;

                v2f w;                              // {W[a][j0], W[a][j1]}
                PK_MUL_S0LO(w, nxv0, p2[0][a]);     // k=0
                PK_FMA_S0HI(w, nxv0, p2[1][a]);     // k=1
                PK_FMA_S0LO(w, nxv1, p2[2][a]);     // k=2
                PK_FMA_S0HI(w, nxv1, p2[3][a]);     // k=3
                PK_FMA_S0LO(w, nxv2, p2[4][a]);     // k=4
                PK_FMA_S0HI(w, nxv2, p2[5][a]);     // k=5
                PK_FMA_S0LO(w, nxv3, p2[6][a]);     // k=6
                PK_FMA_S0HI(w, nxv3, p2[7][a]);     // k=7
                PK_FMA_S0LO(w, nxv4, p2[8][a]);     // k=8
                PK_FMA_S0HI(w, nxv4, p2[9][a]);     // k=9

                if (a == 0) {
                    PK_MUL_S1LO(m2[0][0], c0, w);  PK_MUL_S1HI(m2[1][0], c0, w);
                    PK_MUL_S1LO(m2[0][1], c1, w);  PK_MUL_S1HI(m2[1][1], c1, w);
                    PK_MUL_S1LO(m2[0][2], c2, w);  PK_MUL_S1HI(m2[1][2], c2, w);
                    PK_MUL_S1LO(m2[0][3], c3, w);  PK_MUL_S1HI(m2[1][3], c3, w);
                    PK_MUL_S1LO(m2[0][4], c4, w);  PK_MUL_S1HI(m2[1][4], c4, w);
                } else {
                    PK_FMA_S1LO(m2[0][0], c0, w);  PK_FMA_S1HI(m2[1][0], c0, w);
                    PK_FMA_S1LO(m2[0][1], c1, w);  PK_FMA_S1HI(m2[1][1], c1, w);
                    PK_FMA_S1LO(m2[0][2], c2, w);  PK_FMA_S1HI(m2[1][2], c2, w);
                    PK_FMA_S1LO(m2[0][3], c3, w);  PK_FMA_S1HI(m2[1][3], c3, w);
                    PK_FMA_S1LO(m2[0][4], c4, w);  PK_FMA_S1HI(m2[1][4], c4, w);
                }
            }

            nxv0 = px0; nxv1 = px1; nxv2 = px2; nxv3 = px3; nxv4 = px4;
            __builtin_amdgcn_wave_barrier();   // reads before next step's writes
        }
    }

    // ---- in-block ordered tree: 96 chunk matrices -> 1 --------------------
    __syncthreads();                  // main-loop LDS region now dead
    if (active) {
        // stage own columns into ROW-major tree slot cib (stride 120, rows 12)
        float* t = lds + cib * 120;
#pragma unroll
        for (int i = 0; i < 5; ++i) {
            t[(2 * i)     * 12 + j0] = m2[0][i].x;
            t[(2 * i + 1) * 12 + j0] = m2[0][i].y;
            t[(2 * i)     * 12 + j1] = m2[1][i].x;
            t[(2 * i + 1) * 12 + j1] = m2[1][i].y;
        }
    }
    __syncthreads();

    // thread-per-row tree products: 96 -> 48 -> 24 -> 12 -> 6 -> 3 (ping-pong)
    {
        const float* src = lds;
        float* dst = lds + 11520;
        int n = 96;
        while (n > 3) {
            const int np = n >> 1;
            const int pI = tid / TEN;
            const int r  = tid % TEN;
            if (pI < np) {
                const float* A = src + (2 * pI) * 120;
                const float* B = src + (2 * pI + 1) * 120;
                float ar[TEN];
#pragma unroll
                for (int j = 0; j < TEN; ++j) ar[j] = A[r * 12 + j];
                float c[TEN] = {0, 0, 0, 0, 0, 0, 0, 0, 0, 0};
#pragma unroll
                for (int a = 0; a < TEN; ++a) {
                    const float ma = ar[a];
#pragma unroll
                    for (int j = 0; j < TEN; ++j) c[j] = fmaf(ma, B[a * 12 + j], c[j]);
                }
                float* Cp = dst + pI * 120;
#pragma unroll
                for (int j = 0; j < TEN; ++j) Cp[r * 12 + j] = c[j];
            }
            __syncthreads();
            const float* ts = src; src = dst; dst = const_cast<float*>(ts);
            n = np;
        }
        // 3 matrices left at src. tmp = the other ping-pong buffer (dead).
        float* tmp = (src == lds) ? lds + 11520 : lds;
        if (tid < TEN) {
            const int r = tid;
            float ar[TEN];
#pragma unroll
            for (int j = 0; j < TEN; ++j) ar[j] = src[r * 12 + j];
            float c[TEN] = {0, 0, 0, 0, 0, 0, 0, 0, 0, 0};
#pragma unroll
            for (int a = 0; a < TEN; ++a) {
                const float ma = ar[a];
#pragma unroll
                for (int j = 0; j < TEN; ++j) c[j] = fmaf(ma, src[120 + a * 12 + j], c[j]);
            }
#pragma unroll
            for (int j = 0; j < TEN; ++j) tmp[r * 12 + j] = c[j];
        }
        __syncthreads();
        if (tid < TEN) {
            const int r = tid;
            float c[TEN] = {0, 0, 0, 0, 0, 0, 0, 0, 0, 0};
#pragma unroll
            for (int a = 0; a < TEN; ++a) {
                const float ma = tmp[r * 12 + a];
#pragma unroll
                for (int j = 0; j < TEN; ++j) c[j] = fmaf(ma, src[240 + a * 12 + j], c[j]);
            }
            float* dr = outBlk + (size_t)blockIdx.x * 100 + r * TEN;
#pragma unroll
            for (int j = 0; j < TEN; ++j) dr[j] = c[j];
        }
    }
}

// ---------------------------------------------------------------------------
// tree64 helper for the final kernel (row-major slots, stride 120).
// Quad row partition {0,1,2},{3,4,5},{6,7,(dup)},{8,9,(dup)}.
// ---------------------------------------------------------------------------
__device__ __forceinline__ void tree64(float* lds, int tid)
{
    const int q     = tid >> 2;
    const int sub   = tid & 3;
    const int rbase = (sub == 3) ? 8 : sub * 3;
    const int r0 = rbase, r1 = rbase + 1;
    const int r2 = (rbase + 2 > 9) ? 9 : rbase + 2;
    const bool w2 = (sub < 2);

    for (int np = 32; np >= 1; np >>= 1) {
        float c[3][TEN];
        if (q < np) {
            const float* A = lds + (2 * q) * 120;
            const float* B = lds + (2 * q + 1) * 120;
            float ar[3][TEN];
#pragma unroll
            for (int t = 0; t < 3; ++t) {
                const int rt = (t == 0) ? r0 : (t == 1) ? r1 : r2;
                const float4 a0 = reinterpret_cast<const float4*>(A + rt * 12)[0];
                const float4 a1 = reinterpret_cast<const float4*>(A + rt * 12)[1];
                const float2 a2 = reinterpret_cast<const float2*>(A + rt * 12 + 8)[0];
                ar[t][0]=a0.x; ar[t][1]=a0.y; ar[t][2]=a0.z; ar[t][3]=a0.w;
                ar[t][4]=a1.x; ar[t][5]=a1.y; ar[t][6]=a1.z; ar[t][7]=a1.w;
                ar[t][8]=a2.x; ar[t][9]=a2.y;
#pragma unroll
                for (int j = 0; j < TEN; ++j) c[t][j] = 0.0f;
            }
#pragma unroll
            for (int a = 0; a < TEN; ++a) {
                const float4 b0 = reinterpret_cast<const float4*>(B + a * 12)[0];
                const float4 b1 = reinterpret_cast<const float4*>(B + a * 12)[1];
                const float2 b2 = reinterpret_cast<const float2*>(B + a * 12 + 8)[0];
                const float br[TEN] = {b0.x,b0.y,b0.z,b0.w,b1.x,b1.y,b1.z,b1.w,b2.x,b2.y};
#pragma unroll
                for (int t = 0; t < 3; ++t) {
                    const float ma = ar[t][a];
#pragma unroll
                    for (int j = 0; j < TEN; ++j) c[t][j] = fmaf(ma, br[j], c[t][j]);
                }
            }
        }
        __syncthreads();
        if (q < np) {
            float* C = lds + q * 120;
#pragma unroll
            for (int t = 0; t < 3; ++t) {
                const int rt = (t == 0) ? r0 : (t == 1) ? r1 : r2;
                if (t < 2 || w2) {
                    float* cr = C + rt * 12;
                    reinterpret_cast<float4*>(cr)[0] = make_float4(c[t][0], c[t][1], c[t][2], c[t][3]);
                    reinterpret_cast<float4*>(cr)[1] = make_float4(c[t][4], c[t][5], c[t][6], c[t][7]);
                    reinterpret_cast<float2*>(cr + 8)[0] = make_float2(c[t][8], c[t][9]);
                }
            }
        }
        __syncthreads();
    }
}

// ---------------------------------------------------------------------------
// Final: one block. 64 quads chain 4 consecutive block-matrices (256 -> 64),
// tree64 -> 1, then apply start/accept. (r6's final — cheapest measured.)
// ---------------------------------------------------------------------------
__global__ void automaton_final(const float* __restrict__ blkM,
                                const float* __restrict__ start,
                                const float* __restrict__ acc,
                                float* __restrict__ outv)
{
    __shared__ __align__(16) float lds[7680];
    __shared__ float sv[TEN];
    const int tid = threadIdx.x;
    const int q   = tid >> 2;
    const int sub = tid & 3;
    const int rbase = (sub == 3) ? 8 : sub * 3;
    const int rr0 = rbase, rr1 = rbase + 1;
    const int rr2 = (rbase + 2 > 9) ? 9 : rbase + 2;
    const bool w2 = (sub < 2);

    float a[3][TEN];
    {
        const int rr[3] = {rr0, rr1, rr2};
        const float* A0 = blkM + (size_t)(4 * q) * 100;
#pragma unroll
        for (int t = 0; t < 3; ++t) {
            const float2* pp = reinterpret_cast<const float2*>(A0 + rr[t] * TEN);
            const float2 a0 = pp[0], a1 = pp[1], a2 = pp[2], a3 = pp[3], a4 = pp[4];
            a[t][0]=a0.x; a[t][1]=a0.y; a[t][2]=a1.x; a[t][3]=a1.y; a[t][4]=a2.x;
            a[t][5]=a2.y; a[t][6]=a3.x; a[t][7]=a3.y; a[t][8]=a4.x; a[t][9]=a4.y;
        }
    }
#pragma unroll 1
    for (int i = 1; i < 4; ++i) {
        const float* B = blkM + (size_t)(4 * q + i) * 100;
        float c[3][TEN];
#pragma unroll
        for (int t = 0; t < 3; ++t)
#pragma unroll
            for (int j = 0; j < TEN; ++j) c[t][j] = 0.0f;
#pragma unroll
        for (int aa = 0; aa < TEN; ++aa) {
            const float2* br = reinterpret_cast<const float2*>(B + aa * TEN);
            const float2 b0 = br[0], b1 = br[1], b2 = br[2], b3 = br[3], b4 = br[4];
            const float bv[TEN] = {b0.x,b0.y,b1.x,b1.y,b2.x,b2.y,b3.x,b3.y,b4.x,b4.y};
#pragma unroll
            for (int t = 0; t < 3; ++t) {
                const float ma = a[t][aa];
#pragma unroll
                for (int j = 0; j < TEN; ++j) c[t][j] = fmaf(ma, bv[j], c[t][j]);
            }
        }
#pragma unroll
        for (int t = 0; t < 3; ++t)
#pragma unroll
            for (int j = 0; j < TEN; ++j) a[t][j] = c[t][j];
    }
    {
        float* dst = lds + q * 120;
#pragma unroll
        for (int t = 0; t < 3; ++t) {
            const int rt = (t == 0) ? rr0 : (t == 1) ? rr1 : rr2;
            if (t < 2 || w2) {
                float* dr = dst + rt * 12;
                reinterpret_cast<float4*>(dr)[0] = make_float4(a[t][0], a[t][1], a[t][2], a[t][3]);
                reinterpret_cast<float4*>(dr)[1] = make_float4(a[t][4], a[t][5], a[t][6], a[t][7]);
                reinterpret_cast<float2*>(dr + 8)[0] = make_float2(a[t][8], a[t][9]);
            }
        }
    }
    __syncthreads();
    tree64(lds, tid);

    if (tid < TEN) {
        const int j = tid;
        float v = 0.0f;
#pragma unroll
        for (int r = 0; r < TEN; ++r) v = fmaf(start[r], lds[r * 12 + j], v);
        sv[j] = v;
    }
    __syncthreads();
    if (tid == 0) {
        float o0 = 0.0f, o1 = 0.0f;
#pragma unroll
        for (int j = 0; j < TEN; ++j) {
            o0 = fmaf(sv[j], acc[2 * j + 0], o0);
            o1 = fmaf(sv[j], acc[2 * j + 1], o1);
        }
        outv[0] = o0;
        outv[1] = o1;
    }
}

extern "C" void kernel_launch(void* const* d_in, const int* in_sizes, int n_in,
                              void* d_out, int out_size, void* d_ws, size_t ws_size,
                              hipStream_t stream)
{
    const float* x     = (const float*)d_in[0];
    const float* P     = (const float*)d_in[1];
    const float* start = (const float*)d_in[2];
    const float* acc   = (const float*)d_in[3];
    float* out         = (float*)d_out;

    const long long T = (long long)in_sizes[0] / TEN;  // 2,097,152 steps
    const int C = 24576;                               // 96 chunks x 256 blocks

    float* blkM = (float*)d_ws;                        // [256][10][10]

    automaton_chunks<<<256, 512, 0, stream>>>(x, P, blkM, T, C);
    automaton_final<<<1, 256, 0, stream>>>(blkM, start, acc, out);
}

// Round 14
// 268.694 us; speedup vs baseline: 1.0103x; 1.0103x over previous
//
#include <hip/hip_runtime.h>

#define TEN 10

typedef float v2f __attribute__((ext_vector_type(2)));

// ---------------------------------------------------------------------------
// MEASURED OPTIMUM (restored r6 config; e2e 266.76us here, 267.0 in the
// prior session — the only config to reproduce <267):
// Phase A: 5 lanes per chunk, COLUMN ownership. Lane sub owns columns
// j0=2*sub, j1=2*sub+1 of both W_t and M. Packed fp32 VALU (v_pk_fma_f32
// via __builtin_elementwise_fma; per-element summation order unchanged ->
// bit-exact). 1 wave/SIMD, grid 256, C=12288 (Lc~171).
// Session ledger (13 rounds of perturbations, all measured):
//  - 2 HW waves/SIMD: needs op_sel reg diet (r8) -> chunks 173.6 but forces
//    grid 512 -> 512-matrix final (+6.8us) or 512-thread blocks (re-slows
//    chunks to 179.7, r13). Saddle point: r6 config wins e2e.
//  - wall = 51 cyc/chunk-step, invariant across op count (40/36/35),
//    conflicts (7.2M vs 196K both same speed), widths, schedules (read-
//    first, lookahead), stagger, SW-streams. DS-pipe service + VALU with
//    ~zero overlap; every forced-overlap attempt regressed or spilled.
//  - fusion (r11): fixed ~78us harness overhead dominates the gap; fences +
//    last-block fold cost more than the saved launch.
// LDS: M col-major, column stride 12 floats (16B-aligned cols -> pure
// b128/b64), chunk slot stride 132 (<=2-way bank alias = free, proven r9).
// Same-address 5-lane group reads broadcast (breaking it tripled conflicts,
// r4). No __syncthreads in main loop (intra-wave, in-order DS pipe).
// ---------------------------------------------------------------------------
__global__ __attribute__((amdgpu_flat_work_group_size(256, 256),
                          amdgpu_waves_per_eu(1, 1)))
void automaton_chunks(const float* __restrict__ x, const float* __restrict__ P,
                      float* __restrict__ outBlk, long long T, int C)
{
    // main loop: 48 slots * 132 floats = 6336. tree: T0=48*120 @0, T1 @5760.
    __shared__ __align__(16) float lds[8704];

    const int tid  = threadIdx.x;
    const int wave = tid >> 6;
    const int lane = tid & 63;
    const int grp  = lane / 5;        // 0..11 active, 12 => idle lanes 60..63
    const int sub  = lane % 5;
    const bool active = (grp < 12);
    const int cib  = wave * 12 + grp; // chunk within block 0..47
    const int j0 = 2 * sub, j1 = j0 + 1;

    v2f p2[TEN][TEN];                 // p2[k][a] = {P[k][a][j0], P[k][a][j1]}
    v2f m2[2][5];                     // m2[c][i] = {M[2i][jc], M[2i+1][jc]}
    long long Lc = 0;
    const float2* xp = nullptr;
    float* slot = lds + (active ? cib : 0) * 132;

    if (active) {
        const long long chunk = (long long)blockIdx.x * 48 + cib;
        const long long s0 = chunk * T / C;
        const long long s1 = (chunk + 1) * T / C;
        Lc = s1 - s0;
        xp = reinterpret_cast<const float2*>(x) + s0 * 5;
#pragma unroll
        for (int k = 0; k < TEN; ++k)
#pragma unroll
            for (int a = 0; a < TEN; ++a) {
                const float2 v = *reinterpret_cast<const float2*>(P + k * 100 + a * TEN + j0);
                p2[k][a].x = v.x;
                p2[k][a].y = v.y;
            }
#pragma unroll
        for (int c = 0; c < 2; ++c)
#pragma unroll
            for (int i = 0; i < 5; ++i) {
                const int jc = 2 * sub + c;
                m2[c][i].x = (2 * i     == jc) ? 1.0f : 0.0f;
                m2[c][i].y = (2 * i + 1 == jc) ? 1.0f : 0.0f;
            }
    }

    float2 nx0, nx1, nx2, nx3, nx4;
    if (active) { nx0 = xp[0]; nx1 = xp[1]; nx2 = xp[2]; nx3 = xp[3]; nx4 = xp[4]; xp += 5; }

    if (active) {
#pragma unroll 1
        for (long long s = 0; s < Lc; ++s) {
            const float xs[TEN] = {nx0.x, nx0.y, nx1.x, nx1.y, nx2.x,
                                   nx2.y, nx3.x, nx3.y, nx4.x, nx4.y};
            v2f xv2[TEN];
#pragma unroll
            for (int k = 0; k < TEN; ++k) { xv2[k].x = xs[k]; xv2[k].y = xs[k]; }
            if (s + 1 < Lc) {
                nx0 = xp[0]; nx1 = xp[1]; nx2 = xp[2]; nx3 = xp[3]; nx4 = xp[4];
                xp += 5;
            }

            // 1) publish own columns of M_t (col c at offset (2sub+c)*12)
            {
                float* c0 = slot + j0 * 12;
                reinterpret_cast<float4*>(c0)[0] = make_float4(m2[0][0].x, m2[0][0].y, m2[0][1].x, m2[0][1].y);
                reinterpret_cast<float4*>(c0)[1] = make_float4(m2[0][2].x, m2[0][2].y, m2[0][3].x, m2[0][3].y);
                reinterpret_cast<float2*>(c0 + 8)[0] = make_float2(m2[0][4].x, m2[0][4].y);
                float* c1 = slot + j1 * 12;
                reinterpret_cast<float4*>(c1)[0] = make_float4(m2[1][0].x, m2[1][0].y, m2[1][1].x, m2[1][1].y);
                reinterpret_cast<float4*>(c1)[1] = make_float4(m2[1][2].x, m2[1][2].y, m2[1][3].x, m2[1][3].y);
                reinterpret_cast<float2*>(c1 + 8)[0] = make_float2(m2[1][4].x, m2[1][4].y);
            }
            __builtin_amdgcn_wave_barrier();   // write -> read order (in-order DS pipe)

            // 2) build own W columns, packed over {j0,j1}:
            //    w2[a] = sum_k xv2[k] * p2[k][a]   (v_pk_fma_f32)
            v2f w2[TEN];
#pragma unroll
            for (int a = 0; a < TEN; ++a) {
                v2f acc = xv2[0] * p2[0][a];
#pragma unroll
                for (int k = 1; k < TEN; ++k)
                    acc = __builtin_elementwise_fma(xv2[k], p2[k][a], acc);
                w2[a] = acc;
            }

            // 3) M_new[:,own] = M_t @ W[:,own] — stream M columns from LDS,
            //    packed over adjacent rows; accumulate in-place into m2
            //    (m2 regs are dead after the publish).
#pragma unroll
            for (int a = 0; a < TEN; ++a) {
                const float4 v0 = reinterpret_cast<const float4*>(slot + a * 12)[0];
                const float4 v1 = reinterpret_cast<const float4*>(slot + a * 12)[1];
                const float2 v2 = reinterpret_cast<const float2*>(slot + a * 12 + 8)[0];
                v2f cc[5];
                cc[0].x = v0.x; cc[0].y = v0.y;
                cc[1].x = v0.z; cc[1].y = v0.w;
                cc[2].x = v1.x; cc[2].y = v1.y;
                cc[3].x = v1.z; cc[3].y = v1.w;
                cc[4].x = v2.x; cc[4].y = v2.y;
                v2f wb0, wb1;
                wb0.x = w2[a].x; wb0.y = w2[a].x;   // broadcast W[a][j0]
                wb1.x = w2[a].y; wb1.y = w2[a].y;   // broadcast W[a][j1]
                if (a == 0) {
#pragma unroll
                    for (int i = 0; i < 5; ++i) {
                        m2[0][i] = cc[i] * wb0;
                        m2[1][i] = cc[i] * wb1;
                    }
                } else {
#pragma unroll
                    for (int i = 0; i < 5; ++i) {
                        m2[0][i] = __builtin_elementwise_fma(cc[i], wb0, m2[0][i]);
                        m2[1][i] = __builtin_elementwise_fma(cc[i], wb1, m2[1][i]);
                    }
                }
            }
            __builtin_amdgcn_wave_barrier();   // reads before next step's writes
        }
    }

    // ---- in-block ordered tree: 48 chunk matrices -> 1 --------------------
    __syncthreads();                  // main-loop LDS region now dead
    if (active) {
        // stage own columns into ROW-major tree slot cib (stride 120, rows 12)
        float* t = lds + cib * 120;
#pragma unroll
        for (int i = 0; i < 5; ++i) {
            t[(2 * i)     * 12 + j0] = m2[0][i].x;
            t[(2 * i + 1) * 12 + j0] = m2[0][i].y;
            t[(2 * i)     * 12 + j1] = m2[1][i].x;
            t[(2 * i + 1) * 12 + j1] = m2[1][i].y;
        }
    }
    __syncthreads();

    // thread-per-row tree products: 48 -> 24 -> 12 -> 6 -> 3 (ping-pong)
    {
        const float* src = lds;
        float* dst = lds + 5760;
        int n = 48;
        while (n > 3) {
            const int np = n >> 1;
            const int pI = tid / TEN;
            const int r  = tid % TEN;
            if (pI < np) {
                const float* A = src + (2 * pI) * 120;
                const float* B = src + (2 * pI + 1) * 120;
                float ar[TEN];
#pragma unroll
                for (int j = 0; j < TEN; ++j) ar[j] = A[r * 12 + j];
                float c[TEN] = {0, 0, 0, 0, 0, 0, 0, 0, 0, 0};
#pragma unroll
                for (int a = 0; a < TEN; ++a) {
                    const float ma = ar[a];
#pragma unroll
                    for (int j = 0; j < TEN; ++j) c[j] = fmaf(ma, B[a * 12 + j], c[j]);
                }
                float* Cp = dst + pI * 120;
#pragma unroll
                for (int j = 0; j < TEN; ++j) Cp[r * 12 + j] = c[j];
            }
            __syncthreads();
            const float* ts = src; src = dst; dst = const_cast<float*>(ts);
            n = np;
        }
        // 3 matrices left in src (== lds). Serial: (M0*M1)*M2 by 10 threads.
        if (tid < TEN) {
            const int r = tid;
            float ar[TEN];
#pragma unroll
            for (int j = 0; j < TEN; ++j) ar[j] = src[r * 12 + j];
            float c[TEN] = {0, 0, 0, 0, 0, 0, 0, 0, 0, 0};
#pragma unroll
            for (int a = 0; a < TEN; ++a) {
                const float ma = ar[a];
#pragma unroll
                for (int j = 0; j < TEN; ++j) c[j] = fmaf(ma, src[120 + a * 12 + j], c[j]);
            }
#pragma unroll
            for (int j = 0; j < TEN; ++j) lds[5760 + r * 12 + j] = c[j];
        }
        __syncthreads();
        if (tid < TEN) {
            const int r = tid;
            float c[TEN] = {0, 0, 0, 0, 0, 0, 0, 0, 0, 0};
#pragma unroll
            for (int a = 0; a < TEN; ++a) {
                const float ma = lds[5760 + r * 12 + a];
#pragma unroll
                for (int j = 0; j < TEN; ++j) c[j] = fmaf(ma, src[240 + a * 12 + j], c[j]);
            }
            float* dr = outBlk + (size_t)blockIdx.x * 100 + r * TEN;
#pragma unroll
            for (int j = 0; j < TEN; ++j) dr[j] = c[j];
        }
    }
}

// ---------------------------------------------------------------------------
// tree64 helper for the final kernel (row-major slots, stride 120).
// Quad row partition {0,1,2},{3,4,5},{6,7,(dup)},{8,9,(dup)}.
// ---------------------------------------------------------------------------
__device__ __forceinline__ void tree64(float* lds, int tid)
{
    const int q     = tid >> 2;
    const int sub   = tid & 3;
    const int rbase = (sub == 3) ? 8 : sub * 3;
    const int r0 = rbase, r1 = rbase + 1;
    const int r2 = (rbase + 2 > 9) ? 9 : rbase + 2;
    const bool w2 = (sub < 2);

    for (int np = 32; np >= 1; np >>= 1) {
        float c[3][TEN];
        if (q < np) {
            const float* A = lds + (2 * q) * 120;
            const float* B = lds + (2 * q + 1) * 120;
            float ar[3][TEN];
#pragma unroll
            for (int t = 0; t < 3; ++t) {
                const int rt = (t == 0) ? r0 : (t == 1) ? r1 : r2;
                const float4 a0 = reinterpret_cast<const float4*>(A + rt * 12)[0];
                const float4 a1 = reinterpret_cast<const float4*>(A + rt * 12)[1];
                const float2 a2 = reinterpret_cast<const float2*>(A + rt * 12 + 8)[0];
                ar[t][0]=a0.x; ar[t][1]=a0.y; ar[t][2]=a0.z; ar[t][3]=a0.w;
                ar[t][4]=a1.x; ar[t][5]=a1.y; ar[t][6]=a1.z; ar[t][7]=a1.w;
                ar[t][8]=a2.x; ar[t][9]=a2.y;
#pragma unroll
                for (int j = 0; j < TEN; ++j) c[t][j] = 0.0f;
            }
#pragma unroll
            for (int a = 0; a < TEN; ++a) {
                const float4 b0 = reinterpret_cast<const float4*>(B + a * 12)[0];
                const float4 b1 = reinterpret_cast<const float4*>(B + a * 12)[1];
                const float2 b2 = reinterpret_cast<const float2*>(B + a * 12 + 8)[0];
                const float br[TEN] = {b0.x,b0.y,b0.z,b0.w,b1.x,b1.y,b1.z,b1.w,b2.x,b2.y};
#pragma unroll
                for (int t = 0; t < 3; ++t) {
                    const float ma = ar[t][a];
#pragma unroll
                    for (int j = 0; j < TEN; ++j) c[t][j] = fmaf(ma, br[j], c[t][j]);
                }
            }
        }
        __syncthreads();
        if (q < np) {
            float* C = lds + q * 120;
#pragma unroll
            for (int t = 0; t < 3; ++t) {
                const int rt = (t == 0) ? r0 : (t == 1) ? r1 : r2;
                if (t < 2 || w2) {
                    float* cr = C + rt * 12;
                    reinterpret_cast<float4*>(cr)[0] = make_float4(c[t][0], c[t][1], c[t][2], c[t][3]);
                    reinterpret_cast<float4*>(cr)[1] = make_float4(c[t][4], c[t][5], c[t][6], c[t][7]);
                    reinterpret_cast<float2*>(cr + 8)[0] = make_float2(c[t][8], c[t][9]);
                }
            }
        }
        __syncthreads();
    }
}

// ---------------------------------------------------------------------------
// Final: one block. 64 quads chain 4 consecutive block-matrices (256 -> 64),
// tree64 -> 1, then apply start/accept. (Cheapest final measured.)
// ---------------------------------------------------------------------------
__global__ void automaton_final(const float* __restrict__ blkM,
                                const float* __restrict__ start,
                                const float* __restrict__ acc,
                                float* __restrict__ outv)
{
    __shared__ __align__(16) float lds[7680];
    __shared__ float sv[TEN];
    const int tid = threadIdx.x;
    const int q   = tid >> 2;
    const int sub = tid & 3;
    const int rbase = (sub == 3) ? 8 : sub * 3;
    const int rr0 = rbase, rr1 = rbase + 1;
    const int rr2 = (rbase + 2 > 9) ? 9 : rbase + 2;
    const bool w2 = (sub < 2);

    float a[3][TEN];
    {
        const int rr[3] = {rr0, rr1, rr2};
        const float* A0 = blkM + (size_t)(4 * q) * 100;
#pragma unroll
        for (int t = 0; t < 3; ++t) {
            const float2* pp = reinterpret_cast<const float2*>(A0 + rr[t] * TEN);
            const float2 a0 = pp[0], a1 = pp[1], a2 = pp[2], a3 = pp[3], a4 = pp[4];
            a[t][0]=a0.x; a[t][1]=a0.y; a[t][2]=a1.x; a[t][3]=a1.y; a[t][4]=a2.x;
            a[t][5]=a2.y; a[t][6]=a3.x; a[t][7]=a3.y; a[t][8]=a4.x; a[t][9]=a4.y;
        }
    }
#pragma unroll 1
    for (int i = 1; i < 4; ++i) {
        const float* B = blkM + (size_t)(4 * q + i) * 100;
        float c[3][TEN];
#pragma unroll
        for (int t = 0; t < 3; ++t)
#pragma unroll
            for (int j = 0; j < TEN; ++j) c[t][j] = 0.0f;
#pragma unroll
        for (int aa = 0; aa < TEN; ++aa) {
            const float2* br = reinterpret_cast<const float2*>(B + aa * TEN);
            const float2 b0 = br[0], b1 = br[1], b2 = br[2], b3 = br[3], b4 = br[4];
            const float bv[TEN] = {b0.x,b0.y,b1.x,b1.y,b2.x,b2.y,b3.x,b3.y,b4.x,b4.y};
#pragma unroll
            for (int t = 0; t < 3; ++t) {
                const float ma = a[t][aa];
#pragma unroll
                for (int j = 0; j < TEN; ++j) c[t][j] = fmaf(ma, bv[j], c[t][j]);
            }
        }
#pragma unroll
        for (int t = 0; t < 3; ++t)
#pragma unroll
            for (int j = 0; j < TEN; ++j) a[t][j] = c[t][j];
    }
    {
        float* dst = lds + q * 120;
#pragma unroll
        for (int t = 0; t < 3; ++t) {
            const int rt = (t == 0) ? rr0 : (t == 1) ? rr1 : rr2;
            if (t < 2 || w2) {
                float* dr = dst + rt * 12;
                reinterpret_cast<float4*>(dr)[0] = make_float4(a[t][0], a[t][1], a[t][2], a[t][3]);
                reinterpret_cast<float4*>(dr)[1] = make_float4(a[t][4], a[t][5], a[t][6], a[t][7]);
                reinterpret_cast<float2*>(dr + 8)[0] = make_float2(a[t][8], a[t][9]);
            }
        }
    }
    __syncthreads();
    tree64(lds, tid);

    if (tid < TEN) {
        const int j = tid;
        float v = 0.0f;
#pragma unroll
        for (int r = 0; r < TEN; ++r) v = fmaf(start[r], lds[r * 12 + j], v);
        sv[j] = v;
    }
    __syncthreads();
    if (tid == 0) {
        float o0 = 0.0f, o1 = 0.0f;
#pragma unroll
        for (int j = 0; j < TEN; ++j) {
            o0 = fmaf(sv[j], acc[2 * j + 0], o0);
            o1 = fmaf(sv[j], acc[2 * j + 1], o1);
        }
        outv[0] = o0;
        outv[1] = o1;
    }
}

extern "C" void kernel_launch(void* const* d_in, const int* in_sizes, int n_in,
                              void* d_out, int out_size, void* d_ws, size_t ws_size,
                              hipStream_t stream)
{
    const float* x     = (const float*)d_in[0];
    const float* P     = (const float*)d_in[1];
    const float* start = (const float*)d_in[2];
    const float* acc   = (const float*)d_in[3];
    float* out         = (float*)d_out;

    const long long T = (long long)in_sizes[0] / TEN;  // 2,097,152 steps
    const int C = 12288;                               // 48 chunks x 256 blocks

    float* blkM = (float*)d_ws;                        // [256][10][10]

    automaton_chunks<<<256, 256, 0, stream>>>(x, P, blkM, T, C);
    automaton_final<<<1, 256, 0, stream>>>(blkM, start, acc, out);
}